// Round 11
// baseline (344.018 us; speedup 1.0000x reference)
//
#include <hip/hip_runtime.h>

#define U 128
#define BATCH 2048
#define NL 8
#define NS 8                       /* NS=15 vs 10 bit-identical -> contraction <=0.36; NS=8 residual <1e-3 */
#define DTc 0.1f
#define TENf 10.0f                 /* DT/EPS */
#define INVC (1.0f/11.0f)          /* 1/(1+DT/EPS) */
#define AFACT (0.01f/11.0f)        /* DT^2 / c */

typedef unsigned short u16;
typedef unsigned int u32;
typedef __attribute__((ext_vector_type(8))) short bf16x8;
typedef __attribute__((ext_vector_type(4))) float f32x4;
#define MFMA16(a,b,c) __builtin_amdgcn_mfma_f32_16x16x32_bf16(a,b,c,0,0,0)

/* XOR-swizzled u16 index into a 128x128 LDS tile (prep only) */
#define SWZ8(row, c8)  (((row)<<7) + ((((c8) ^ ((row)&7)))<<3))
#define SWZE(row, col) (SWZ8(row, (col)>>3) + ((col)&7))

__device__ __forceinline__ float bf2f(u16 h){ return __uint_as_float(((u32)h)<<16); }
__device__ __forceinline__ u16 f2bf(float f){
  u32 u = __float_as_uint(f);
  u += 0x7FFFu + ((u >> 16) & 1u);
  return (u16)(u >> 16);
}
__device__ __forceinline__ float fast_tanh(float x){
  float e = __expf(2.0f*x);
  return 1.0f - __fdividef(2.0f, e + 1.0f);
}
__device__ __forceinline__ int detect_md(const u16* x, int* s_bad, int t, int nthr){
  if(t==0) *s_bad = 0;
  __syncthreads();
  int f=0;
  for(int i=t;i<4096;i+=nthr){ float v = bf2f(x[i]); if(!(fabsf(v)<16.0f)) f=1; }
  if(f) atomicOr(s_bad,1);
  __syncthreads();
  return *s_bad ? 0 : 1;   // 1 = bf16 inputs
}
__device__ __forceinline__ bf16x8 ld8f(const float* p){
  float4 f0 = *(const float4*)p, f1 = *(const float4*)(p+4);
  bf16x8 v;
  v[0]=(short)f2bf(f0.x); v[1]=(short)f2bf(f0.y); v[2]=(short)f2bf(f0.z); v[3]=(short)f2bf(f0.w);
  v[4]=(short)f2bf(f1.x); v[5]=(short)f2bf(f1.y); v[6]=(short)f2bf(f1.z); v[7]=(short)f2bf(f1.w);
  return v;
}
// LDS-only barrier (does not drain vmcnt -> global prefetch rides across).
__device__ __forceinline__ void lgkm_barrier(){
  __builtin_amdgcn_sched_barrier(0);
  asm volatile("s_waitcnt lgkmcnt(0)\n\ts_barrier" ::: "memory");
  __builtin_amdgcn_sched_barrier(0);
}

// ---------------- prepB: one kernel, 64 independent blocks (R10, proven) -----
template<typename GB, typename EPI>
__device__ __forceinline__ void gfull(const u16* __restrict__ A, GB getB, EPI epi,
                                      int w, int ln, int lq){
  const int n0 = 16*w + ln;
  bf16x8 bfr[4];
  #pragma unroll
  for(int kt=0;kt<4;kt++) bfr[kt] = getB(n0, kt*32 + lq*8);
  #pragma unroll 2
  for(int rt=0; rt<8; rt++){
    f32x4 acc = {0,0,0,0};
    #pragma unroll
    for(int kt=0;kt<4;kt++){
      bf16x8 af = *(const bf16x8*)&A[SWZ8(rt*16+ln, kt*4+lq)];
      acc = MFMA16(af, bfr[kt], acc);
    }
    epi(acc, rt*16 + lq*4, n0);
  }
}

__global__ __launch_bounds__(512) void prepB(
    const void* __restrict__ xraw, const void* __restrict__ wb,
    u16* __restrict__ Fsw, u16* __restrict__ Wfr){
  __shared__ u16 bufA[16384];   // Wt -> S   (swizzled)
  __shared__ u16 bufB[16384];   // P  -> Q   (swizzled)
  const int t = threadIdx.x;
  const int lane = t & 63, w = t >> 6, ln = lane & 15, lq = lane >> 4;
  const int L = blockIdx.x >> 3, mt = blockIdx.x & 7;
  const int md = detect_md((const u16*)xraw, (int*)bufA, t, 512);
  __syncthreads();   // s_bad overlays bufA
  const u16*   wbb = (const u16*)wb   + ((size_t)L<<14);
  const float* wbf = (const float*)wb + ((size_t)L<<14);

  // W-row fragment gather: block mt writes wave-mt's frags for layer L.
  if(t < 256){
    int kt = t >> 6, lanei = t & 63, lni = lanei & 15, lqi = lanei >> 4;
    bf16x8 v = md ? *(const bf16x8*)&wbb[(16*mt+lni)*U + 32*kt + 8*lqi]
                  : ld8f(wbf + (16*mt+lni)*U + 32*kt + 8*lqi);
    *(bf16x8*)&Wfr[((size_t)L*2048 + mt*256 + t)*8] = v;
  }

  // Wt (= f2bf(W) transposed) -> bufA
  for(int j8=t; j8<2048; j8+=512){
    int n = j8 >> 4, k0 = (j8 & 15) * 8;
    bf16x8 v = md ? *(const bf16x8*)&wbb[j8*8] : ld8f(wbf + j8*8);
    #pragma unroll
    for(int m=0;m<8;m++) bufA[SWZE(k0+m, n)] = (u16)v[m];
  }
  __syncthreads();

  auto gA = [&](int n,int k0)->bf16x8{ return *(const bf16x8*)&bufA[SWZ8(n, k0>>3)]; };
  auto gB = [&](int n,int k0)->bf16x8{ return *(const bf16x8*)&bufB[SWZ8(n, k0>>3)]; };
  auto gW = [&](int n,int k0)->bf16x8{
    if(md) return *(const bf16x8*)&wbb[n*U+k0];
    return ld8f(wbf + n*U + k0);
  };

  // P = AFACT * Wt @ Wt^T  -> bufB
  gfull(bufA, gA, [&](f32x4 acc, int rowb, int n0){
    #pragma unroll
    for(int r=0;r<4;r++) bufB[SWZE(rowb+r, n0)] = f2bf(AFACT*acc[r]);
  }, w, ln, lq);
  __syncthreads();
  // S = INVC*(I - P + P@P)  -> bufA
  gfull(bufB, gB, [&](f32x4 acc, int rowb, int n0){
    #pragma unroll
    for(int r=0;r<4;r++){
      int row = rowb + r;
      bufA[SWZE(row, n0)] = f2bf(INVC*(((row==n0)?1.0f:0.0f) - bf2f(bufB[SWZE(row, n0)]) + acc[r]));
    }
  }, w, ln, lq);
  __syncthreads();
  // Q = DT * S @ W^T  -> bufB
  gfull(bufA, gW, [&](f32x4 acc, int rowb, int n0){
    #pragma unroll
    for(int r=0;r<4;r++) bufB[SWZE(rowb+r, n0)] = f2bf(DTc*acc[r]);
  }, w, ln, lq);
  __syncthreads();

  // swizzle LEFT F frags: quadrants F00 (S, kt 0-3) / F01 (Q, kt 4-7)
  for(int i = mt*1024 + t; i < (mt+1)*1024; i += 512){
    int wf = (i>>11)&3;
    if(wf >= 2) continue;
    int lanei = i & 63, kt = (i>>6)&7, c = (i>>9)&3;
    int row_n = 64*wf + 16*c + (lanei & 15);
    int c8 = kt*4 + (lanei >> 4);
    bf16x8 v = (kt < 4) ? *(const bf16x8*)&bufA[SWZ8(row_n, c8)]
                        : *(const bf16x8*)&bufB[SWZ8(row_n, c8-16)];
    *(bf16x8*)&Fsw[((size_t)L*8192 + i)*8] = v;
  }
}

// ---------------- mainH: 16 rows/block, 8 dual-role waves --------------------
// R10 structure + (a) fragment-major At/H in LDS: reads identity-coalesced
// (conflict-free), writes 4-way scalar; (b) zh history in REGISTERS via fully
// unrolled 8-step layer cycle (all indices compile-time, rule #20). LDS
// 56->21 KB, kills the 8-way read conflicts (AST/HST were both ==4 mod 32
// dwords). Bit-identical to R10 (same chains, same f2bf points).
__global__ __launch_bounds__(512,2) void mainH(
    const void* __restrict__ xraw, const void* __restrict__ w_in,
    const void* __restrict__ b_in, const void* __restrict__ bb,
    const bf16x8* __restrict__ Fsw, const bf16x8* __restrict__ Wfr,
    const void* __restrict__ w_out, const void* __restrict__ b_out,
    void* __restrict__ outraw){
  __shared__ u16 Atf[2][4096];   // ping-pong A-fragments (8 frags x 64 lanes x 8)
  __shared__ u16 Hf[2048];       // H fragments (4 frags)
  __shared__ float lg[16*12];
  __shared__ int s_bad;
  float* uout = (float*)&Atf[0][0];   // 8 KB, used after last step only

  const int t = threadIdx.x;
  const int lane = t & 63, w = t >> 6, ln = lane & 15, lq = lane >> 4;
  const int r0 = blockIdx.x * 16;
  const int n = 16*w + ln;            // this lane's column (both roles)

  const int md = detect_md((const u16*)xraw, &s_bad, t, 512);
  float bbLr[NL];
  #pragma unroll
  for(int l=0;l<NL;l++)
    bbLr[l] = DTc * (md ? bf2f(((const u16*)bb)[l*U+n]) : ((const float*)bb)[l*U+n]);

  // ---- phase 1: z1 = x @ w_in^T + b_in -> zr[4] (registers) ----
  float zr[4];
  {
    const u16*   wrb = (const u16*)w_in   + (size_t)n*784;
    const float* wrf = (const float*)w_in + (size_t)n*784;
    const u16*   xrb = (const u16*)xraw   + (size_t)(r0+ln)*784;
    const float* xrf = (const float*)xraw + (size_t)(r0+ln)*784;
    f32x4 acc = {0,0,0,0};
    const bf16x8 z8 = {0,0,0,0,0,0,0,0};
    if(md){
      #pragma unroll
      for(int kt=0; kt<24; ++kt){
        int k0 = kt*32 + lq*8;
        acc = MFMA16(*(const bf16x8*)(xrb + k0), *(const bf16x8*)(wrb + k0), acc);
      }
      { int k0 = 768 + lq*8;
        bf16x8 av = z8, bv = z8;
        if(lq < 2){ av = *(const bf16x8*)(xrb + k0); bv = *(const bf16x8*)(wrb + k0); }
        acc = MFMA16(av, bv, acc);
      }
    } else {
      #pragma unroll 4
      for(int kt=0; kt<24; ++kt){
        int k0 = kt*32 + lq*8;
        acc = MFMA16(ld8f(xrf + k0), ld8f(wrf + k0), acc);
      }
      { int k0 = 768 + lq*8;
        bf16x8 av = z8, bv = z8;
        if(lq < 2){ av = ld8f(xrf + k0); bv = ld8f(wrf + k0); }
        acc = MFMA16(av, bv, acc);
      }
    }
    float bi = md ? bf2f(((const u16*)b_in)[n]) : ((const float*)b_in)[n];
    #pragma unroll
    for(int r=0;r<4;r++) zr[r] = acc[r] + bi;
  }

  // fragment-write base for this lane: element (row=lq*4+r, k=n [+128]) lives
  // at frag kt=k>>5, idx = kt*512 + (((k>>3)&3)*16 + row)*8 + (k&7)
  const int kT = n >> 5;                       // 0..3
  const int wbase = ((n>>3)&3)*128 + lq*32 + (n&7);

  // ---- init: zh history (registers, bf16-rounded), At(0), ru ----
  float zh[NL][4];
  #pragma unroll
  for(int l=0;l<NL;l++){
    #pragma unroll
    for(int r=0;r<4;r++) zh[l][r] = bf2f(f2bf(zr[r]));
  }
  float ru[4];
  #pragma unroll
  for(int r=0;r<4;r++){
    Atf[0][kT*512 + wbase + r*8] = f2bf((TENf + 1.0f) * fast_tanh(zr[r]));
    float v = zr[r] + bbLr[0];
    ru[r] = v;
    Atf[0][(4+kT)*512 + wbase + r*8] = f2bf(v);
  }
  const bf16x8* fbase = Fsw + (w>>2)*2048 + (w&3)*512 + lane;  // left F frags
  const bf16x8* wfb   = Wfr + w*256 + lane;                    // W-row frags
  bf16x8 BfA[8], BfB[8], WfA[4], WfB[4];
  #pragma unroll
  for(int kt=0;kt<8;kt++) BfA[kt] = fbase[kt*64];
  #pragma unroll
  for(int kt=0;kt<4;kt++) WfA[kt] = wfb[kt*64];
  __syncthreads();

#define STEPB(L_, ITV, BC, BN, WC, WN, CURC) { \
    const bool last = ((L_)==7) && ((ITV) == NS-1); \
    { const bf16x8* fp = fbase + (((L_)+1)&7)*8192; \
      _Pragma("unroll") \
      for(int kt=0;kt<8;kt++) BN[kt] = fp[kt*64]; \
      const bf16x8* wp = wfb + (((L_)+1)&7)*2048; \
      _Pragma("unroll") \
      for(int kt=0;kt<4;kt++) WN[kt] = wp[kt*64]; } \
    bf16x8 at8[8]; \
    _Pragma("unroll") \
    for(int kt=0;kt<8;kt++) at8[kt] = *(const bf16x8*)&Atf[CURC][kt*512 + lane*8]; \
    float th[4]; \
    if(!last){ \
      _Pragma("unroll") \
      for(int r=0;r<4;r++) th[r] = TENf * fast_tanh(zh[((L_)+1)&7][r]); \
    } \
    f32x4 accL = {0,0,0,0}; \
    _Pragma("unroll") \
    for(int kt=0;kt<8;kt++) accL = MFMA16(at8[kt], BC[kt], accL); \
    _Pragma("unroll") \
    for(int r=0;r<4;r++) Hf[kT*512 + wbase + r*8] = f2bf(accL[r]); \
    lgkm_barrier(); \
    bf16x8 hf[4]; \
    _Pragma("unroll") \
    for(int kt=0;kt<4;kt++) hf[kt] = *(const bf16x8*)&Hf[kt*512 + lane*8]; \
    f32x4 accR = {0,0,0,0}; \
    _Pragma("unroll") \
    for(int kt=0;kt<4;kt++) accR = MFMA16(hf[kt], WC[kt], accR); \
    if(!last){ \
      _Pragma("unroll") \
      for(int r=0;r<4;r++){ \
        float base = ((L_)==7) ? fast_tanh(zr[r]) : accL[r]; \
        Atf[1-(CURC)][kT*512 + wbase + r*8] = f2bf(th[r] + base); \
      } \
      _Pragma("unroll") \
      for(int r=0;r<4;r++){ \
        float yu = ru[r] - DTc*accR[r]; \
        zh[(L_)][r] = bf2f(f2bf(yu)); \
        float rn = ((L_)==7) ? (zr[r] + bbLr[0]) : (yu + bbLr[((L_)+1)&7]); \
        ru[r] = rn; \
        Atf[1-(CURC)][(4+kT)*512 + wbase + r*8] = f2bf(rn); \
      } \
    } else { \
      _Pragma("unroll") \
      for(int r=0;r<4;r++) uout[(lq*4+r)*U + n] = zr[r] + bbLr[7] - DTc*accR[r]; \
    } \
    lgkm_barrier(); \
  }

  for(int it=0; it<NS; ++it){
    STEPB(0, it, BfA, BfB, WfA, WfB, 0)
    STEPB(1, it, BfB, BfA, WfB, WfA, 1)
    STEPB(2, it, BfA, BfB, WfA, WfB, 0)
    STEPB(3, it, BfB, BfA, WfB, WfA, 1)
    STEPB(4, it, BfA, BfB, WfA, WfB, 0)
    STEPB(5, it, BfB, BfA, WfB, WfA, 1)
    STEPB(6, it, BfA, BfB, WfA, WfB, 0)
    STEPB(7, it, BfB, BfA, WfB, WfA, 1)
  }
#undef STEPB

  // ---- logits + softmax ----
  if(t < 160){
    int mm = t/10, o = t - mm*10;
    float a = md ? bf2f(((const u16*)b_out)[o]) : ((const float*)b_out)[o];
    if(md){
      const u16* wo = (const u16*)w_out + o*U;
      for(int k=0;k<U;k++) a += uout[mm*U + k]*bf2f(wo[k]);
    } else {
      const float* wo = (const float*)w_out + o*U;
      for(int k=0;k<U;k++) a += uout[mm*U + k]*wo[k];
    }
    lg[mm*12 + o] = a;
  }
  __syncthreads();
  if(t < 16){
    float mx = -1e30f;
    for(int o=0;o<10;o++) mx = fmaxf(mx, lg[t*12 + o]);
    float e[10]; float sum = 0.0f;
    for(int o=0;o<10;o++){ e[o] = __expf(lg[t*12 + o] - mx); sum += e[o]; }
    float inv = 1.0f / sum;
    for(int o=0;o<10;o++){
      float pv = e[o]*inv;
      if(md) ((u16*)outraw)[(size_t)(r0 + t)*10 + o] = f2bf(pv);
      else   ((float*)outraw)[(size_t)(r0 + t)*10 + o] = pv;
    }
  }
}

extern "C" void kernel_launch(void* const* d_in, const int* in_sizes, int n_in,
                              void* d_out, int out_size, void* d_ws, size_t ws_size,
                              hipStream_t stream) {
  char* p = (char*)d_ws;
  u16* Fsw = (u16*)p;  p += (size_t)8*256*256*2;   // 1 MB (left half used)
  u16* Wfr = (u16*)p;  p += (size_t)8*128*128*2;   // 256 KB W-row frags

  prepB<<<64, 512, 0, stream>>>(d_in[0], d_in[3], Fsw, Wfr);
  mainH<<<BATCH/16, 512, 0, stream>>>(d_in[0], d_in[1], d_in[2], d_in[4],
                                      (const bf16x8*)Fsw, (const bf16x8*)Wfr,
                                      d_in[5], d_in[6], d_out);
}

// Round 12
// 184.799 us; speedup vs baseline: 1.8616x; 1.8616x over previous
//
#include <hip/hip_runtime.h>

#define U 128
#define BATCH 2048
#define NL 8
#define NS 8                       /* NS=15 vs 10 bit-identical -> contraction <=0.36; NS=8 residual <1e-3 */
#define DTc 0.1f
#define TENf 10.0f                 /* DT/EPS */
#define INVC (1.0f/11.0f)          /* 1/(1+DT/EPS) */
#define AFACT (0.01f/11.0f)        /* DT^2 / c */

typedef unsigned short u16;
typedef unsigned int u32;
typedef __attribute__((ext_vector_type(8))) short bf16x8;
typedef __attribute__((ext_vector_type(4))) float f32x4;
#define MFMA16(a,b,c) __builtin_amdgcn_mfma_f32_16x16x32_bf16(a,b,c,0,0,0)

/* XOR-swizzled u16 index into a 128x128 LDS tile (prep only) */
#define SWZ8(row, c8)  (((row)<<7) + ((((c8) ^ ((row)&7)))<<3))
#define SWZE(row, col) (SWZ8(row, (col)>>3) + ((col)&7))

__device__ __forceinline__ float bf2f(u16 h){ return __uint_as_float(((u32)h)<<16); }
__device__ __forceinline__ u16 f2bf(float f){
  u32 u = __float_as_uint(f);
  u += 0x7FFFu + ((u >> 16) & 1u);
  return (u16)(u >> 16);
}
__device__ __forceinline__ float fast_tanh(float x){
  float e = __expf(2.0f*x);
  return 1.0f - __fdividef(2.0f, e + 1.0f);
}
__device__ __forceinline__ int detect_md(const u16* x, int* s_bad, int t, int nthr){
  if(t==0) *s_bad = 0;
  __syncthreads();
  int f=0;
  for(int i=t;i<4096;i+=nthr){ float v = bf2f(x[i]); if(!(fabsf(v)<16.0f)) f=1; }
  if(f) atomicOr(s_bad,1);
  __syncthreads();
  return *s_bad ? 0 : 1;   // 1 = bf16 inputs
}
__device__ __forceinline__ bf16x8 ld8f(const float* p){
  float4 f0 = *(const float4*)p, f1 = *(const float4*)(p+4);
  bf16x8 v;
  v[0]=(short)f2bf(f0.x); v[1]=(short)f2bf(f0.y); v[2]=(short)f2bf(f0.z); v[3]=(short)f2bf(f0.w);
  v[4]=(short)f2bf(f1.x); v[5]=(short)f2bf(f1.y); v[6]=(short)f2bf(f1.z); v[7]=(short)f2bf(f1.w);
  return v;
}
// LDS-only barrier (does not drain vmcnt -> global prefetch rides across).
__device__ __forceinline__ void lgkm_barrier(){
  __builtin_amdgcn_sched_barrier(0);
  asm volatile("s_waitcnt lgkmcnt(0)\n\ts_barrier" ::: "memory");
  __builtin_amdgcn_sched_barrier(0);
}

// ---------------- prepB: one kernel, 64 independent blocks (proven) ----------
template<typename GB, typename EPI>
__device__ __forceinline__ void gfull(const u16* __restrict__ A, GB getB, EPI epi,
                                      int w, int ln, int lq){
  const int n0 = 16*w + ln;
  bf16x8 bfr[4];
  #pragma unroll
  for(int kt=0;kt<4;kt++) bfr[kt] = getB(n0, kt*32 + lq*8);
  #pragma unroll 2
  for(int rt=0; rt<8; rt++){
    f32x4 acc = {0,0,0,0};
    #pragma unroll
    for(int kt=0;kt<4;kt++){
      bf16x8 af = *(const bf16x8*)&A[SWZ8(rt*16+ln, kt*4+lq)];
      acc = MFMA16(af, bfr[kt], acc);
    }
    epi(acc, rt*16 + lq*4, n0);
  }
}

__global__ __launch_bounds__(512) void prepB(
    const void* __restrict__ xraw, const void* __restrict__ wb,
    u16* __restrict__ Fsw, u16* __restrict__ Wfr){
  __shared__ u16 bufA[16384];   // Wt -> S   (swizzled)
  __shared__ u16 bufB[16384];   // P  -> Q   (swizzled)
  const int t = threadIdx.x;
  const int lane = t & 63, w = t >> 6, ln = lane & 15, lq = lane >> 4;
  const int L = blockIdx.x >> 3, mt = blockIdx.x & 7;
  const int md = detect_md((const u16*)xraw, (int*)bufA, t, 512);
  __syncthreads();   // s_bad overlays bufA
  const u16*   wbb = (const u16*)wb   + ((size_t)L<<14);
  const float* wbf = (const float*)wb + ((size_t)L<<14);

  // W-row fragment gather: block mt writes wave-mt's frags for layer L.
  if(t < 256){
    int kt = t >> 6, lanei = t & 63, lni = lanei & 15, lqi = lanei >> 4;
    bf16x8 v = md ? *(const bf16x8*)&wbb[(16*mt+lni)*U + 32*kt + 8*lqi]
                  : ld8f(wbf + (16*mt+lni)*U + 32*kt + 8*lqi);
    *(bf16x8*)&Wfr[((size_t)L*2048 + mt*256 + t)*8] = v;
  }

  // Wt (= f2bf(W) transposed) -> bufA
  for(int j8=t; j8<2048; j8+=512){
    int n = j8 >> 4, k0 = (j8 & 15) * 8;
    bf16x8 v = md ? *(const bf16x8*)&wbb[j8*8] : ld8f(wbf + j8*8);
    #pragma unroll
    for(int m=0;m<8;m++) bufA[SWZE(k0+m, n)] = (u16)v[m];
  }
  __syncthreads();

  auto gA = [&](int n,int k0)->bf16x8{ return *(const bf16x8*)&bufA[SWZ8(n, k0>>3)]; };
  auto gB = [&](int n,int k0)->bf16x8{ return *(const bf16x8*)&bufB[SWZ8(n, k0>>3)]; };
  auto gW = [&](int n,int k0)->bf16x8{
    if(md) return *(const bf16x8*)&wbb[n*U+k0];
    return ld8f(wbf + n*U + k0);
  };

  // P = AFACT * Wt @ Wt^T  -> bufB
  gfull(bufA, gA, [&](f32x4 acc, int rowb, int n0){
    #pragma unroll
    for(int r=0;r<4;r++) bufB[SWZE(rowb+r, n0)] = f2bf(AFACT*acc[r]);
  }, w, ln, lq);
  __syncthreads();
  // S = INVC*(I - P + P@P)  -> bufA
  gfull(bufB, gB, [&](f32x4 acc, int rowb, int n0){
    #pragma unroll
    for(int r=0;r<4;r++){
      int row = rowb + r;
      bufA[SWZE(row, n0)] = f2bf(INVC*(((row==n0)?1.0f:0.0f) - bf2f(bufB[SWZE(row, n0)]) + acc[r]));
    }
  }, w, ln, lq);
  __syncthreads();
  // Q = DT * S @ W^T  -> bufB
  gfull(bufA, gW, [&](f32x4 acc, int rowb, int n0){
    #pragma unroll
    for(int r=0;r<4;r++) bufB[SWZE(rowb+r, n0)] = f2bf(DTc*acc[r]);
  }, w, ln, lq);
  __syncthreads();

  // swizzle LEFT F frags: quadrants F00 (S, kt 0-3) / F01 (Q, kt 4-7)
  for(int i = mt*1024 + t; i < (mt+1)*1024; i += 512){
    int wf = (i>>11)&3;
    if(wf >= 2) continue;
    int lanei = i & 63, kt = (i>>6)&7, c = (i>>9)&3;
    int row_n = 64*wf + 16*c + (lanei & 15);
    int c8 = kt*4 + (lanei >> 4);
    bf16x8 v = (kt < 4) ? *(const bf16x8*)&bufA[SWZ8(row_n, c8)]
                        : *(const bf16x8*)&bufB[SWZ8(row_n, c8-16)];
    *(bf16x8*)&Fsw[((size_t)L*8192 + i)*8] = v;
  }
}

// ---------------- mainG: 16 rows/block, 8 dual-role waves --------------------
// EXACTLY R10's measured-115.5us kernel with ONE change: At and H tiles are
// stored FRAGMENT-MAJOR in LDS. Reads become contiguous ds_read_b128 at
// kt*512+lane*8 (conflict-free; R10's row-major AST/HST were ==4 mod 32
// dwords -> 8-way conflict on every fragment read). Writes are scalar into
// fragment slots (<=8-way on 8 stores/step — cheap). zh16 unchanged (its
// pattern is already conflict-free). Bit-identical chains.
__global__ __launch_bounds__(512,2) void mainG(
    const void* __restrict__ xraw, const void* __restrict__ w_in,
    const void* __restrict__ b_in, const void* __restrict__ bb,
    const bf16x8* __restrict__ Fsw, const bf16x8* __restrict__ Wfr,
    const void* __restrict__ w_out, const void* __restrict__ b_out,
    void* __restrict__ outraw){
  __shared__ u16 Atf[2][4096];           // ping-pong A-fragments [T(kt0-3) | r(kt4-7)]
  __shared__ u16 zh16[NL][16][132];      // lane-local y_u history (bf16), conflict-free
  __shared__ u16 Hf[2048];               // H fragments (kt 0-3)
  __shared__ float lg[16*12];
  __shared__ int s_bad;
  float* uout = (float*)&Atf[0][0];      // 8 KB, used after last step only

  const int t = threadIdx.x;
  const int lane = t & 63, w = t >> 6, ln = lane & 15, lq = lane >> 4;
  const int r0 = blockIdx.x * 16;
  const int n = 16*w + ln;               // this lane's column (T and u roles)

  const int md = detect_md((const u16*)xraw, &s_bad, t, 512);
  float bbLr[NL];
  #pragma unroll
  for(int l=0;l<NL;l++)
    bbLr[l] = DTc * (md ? bf2f(((const u16*)bb)[l*U+n]) : ((const float*)bb)[l*U+n]);

  // ---- phase 1: z1 = x @ w_in^T + b_in -> zr[4] (registers) ----
  float zr[4];
  {
    const u16*   wrb = (const u16*)w_in   + (size_t)n*784;
    const float* wrf = (const float*)w_in + (size_t)n*784;
    const u16*   xrb = (const u16*)xraw   + (size_t)(r0+ln)*784;
    const float* xrf = (const float*)xraw + (size_t)(r0+ln)*784;
    f32x4 acc = {0,0,0,0};
    const bf16x8 z8 = {0,0,0,0,0,0,0,0};
    if(md){
      #pragma unroll
      for(int kt=0; kt<24; ++kt){
        int k0 = kt*32 + lq*8;
        acc = MFMA16(*(const bf16x8*)(xrb + k0), *(const bf16x8*)(wrb + k0), acc);
      }
      { int k0 = 768 + lq*8;
        bf16x8 av = z8, bv = z8;
        if(lq < 2){ av = *(const bf16x8*)(xrb + k0); bv = *(const bf16x8*)(wrb + k0); }
        acc = MFMA16(av, bv, acc);
      }
    } else {
      #pragma unroll 4
      for(int kt=0; kt<24; ++kt){
        int k0 = kt*32 + lq*8;
        acc = MFMA16(ld8f(xrf + k0), ld8f(wrf + k0), acc);
      }
      { int k0 = 768 + lq*8;
        bf16x8 av = z8, bv = z8;
        if(lq < 2){ av = ld8f(xrf + k0); bv = ld8f(wrf + k0); }
        acc = MFMA16(av, bv, acc);
      }
    }
    float bi = md ? bf2f(((const u16*)b_in)[n]) : ((const float*)b_in)[n];
    #pragma unroll
    for(int r=0;r<4;r++) zr[r] = acc[r] + bi;
  }

  // fragment-slot base: element (row=lq*4+r, k) lives at frag kt=k>>5,
  // slot lane' = ((k>>3)&3)*16 + row, elem k&7. For this lane's column n:
  const int kT = n >> 5;                             // frag (T); +4 for r-part
  const int wbase = ((n>>3)&3)*128 + lq*32 + (n&7);  // lane'*8 + elem (r via +8r)

  // ---- init: zh history, At(0), ru regs (all from local zr) ----
  #pragma unroll
  for(int l=0;l<NL;l++){
    #pragma unroll
    for(int r=0;r<4;r++) zh16[l][lq*4+r][n] = f2bf(zr[r]);
  }
  float ru[4];
  #pragma unroll
  for(int r=0;r<4;r++){
    Atf[0][kT*512 + wbase + r*8] = f2bf((TENf + 1.0f) * fast_tanh(zr[r]));
    float v = zr[r] + bbLr[0];
    ru[r] = v;
    Atf[0][(4+kT)*512 + wbase + r*8] = f2bf(v);
  }
  const bf16x8* fbase = Fsw + (w>>2)*2048 + (w&3)*512 + lane;  // left F frags
  const bf16x8* wfb   = Wfr + w*256 + lane;                    // W-row frags
  bf16x8 BfA[8], BfB[8], WfA[4], WfB[4];
  #pragma unroll
  for(int kt=0;kt<8;kt++) BfA[kt] = fbase[kt*64];
  #pragma unroll
  for(int kt=0;kt<4;kt++) WfA[kt] = wfb[kt*64];
  __syncthreads();

#define STEPBODY(STEPV, BC, BN, WC, WN, CURC) { \
    const int l = (STEPV) & 7; \
    const int lnext = (l+1) & 7; \
    const bool last = ((STEPV) == NS*NL-1); \
    const bool wrap = (l == 7); \
    { const bf16x8* fp = fbase + lnext*8192; \
      _Pragma("unroll") \
      for(int kt=0;kt<8;kt++) BN[kt] = fp[kt*64]; \
      const bf16x8* wp = wfb + lnext*2048; \
      _Pragma("unroll") \
      for(int kt=0;kt<4;kt++) WN[kt] = wp[kt*64]; } \
    bf16x8 at8[8]; \
    _Pragma("unroll") \
    for(int kt=0;kt<8;kt++) at8[kt] = *(const bf16x8*)&Atf[CURC][kt*512 + lane*8]; \
    float th[4]; \
    if(!last){ \
      _Pragma("unroll") \
      for(int r=0;r<4;r++) th[r] = TENf * fast_tanh(bf2f(zh16[lnext][lq*4 + r][n])); \
    } \
    f32x4 accL = {0,0,0,0}; \
    _Pragma("unroll") \
    for(int kt=0;kt<8;kt++) accL = MFMA16(at8[kt], BC[kt], accL); \
    _Pragma("unroll") \
    for(int r=0;r<4;r++) Hf[kT*512 + wbase + r*8] = f2bf(accL[r]); \
    lgkm_barrier(); \
    bf16x8 hf[4]; \
    _Pragma("unroll") \
    for(int kt=0;kt<4;kt++) hf[kt] = *(const bf16x8*)&Hf[kt*512 + lane*8]; \
    f32x4 accR = {0,0,0,0}; \
    _Pragma("unroll") \
    for(int kt=0;kt<4;kt++) accR = MFMA16(hf[kt], WC[kt], accR); \
    if(!last){ \
      _Pragma("unroll") \
      for(int r=0;r<4;r++){ \
        float base = wrap ? fast_tanh(zr[r]) : accL[r]; \
        Atf[1-(CURC)][kT*512 + wbase + r*8] = f2bf(th[r] + base); \
      } \
      _Pragma("unroll") \
      for(int r=0;r<4;r++){ \
        float yu = ru[r] - DTc*accR[r]; \
        zh16[l][lq*4 + r][n] = f2bf(yu); \
        float rn = wrap ? (zr[r] + bbLr[0]) : (yu + bbLr[(l+1)&7]); \
        ru[r] = rn; \
        Atf[1-(CURC)][(4+kT)*512 + wbase + r*8] = f2bf(rn); \
      } \
    } else { \
      _Pragma("unroll") \
      for(int r=0;r<4;r++) uout[(lq*4+r)*U + n] = zr[r] + bbLr[7] - DTc*accR[r]; \
    } \
    lgkm_barrier(); \
  }

  for(int sp=0; sp<NS*NL; sp+=2){
    STEPBODY(sp,   BfA, BfB, WfA, WfB, 0)
    STEPBODY(sp+1, BfB, BfA, WfB, WfA, 1)
  }
#undef STEPBODY

  // ---- logits + softmax ----
  if(t < 160){
    int mm = t/10, o = t - mm*10;
    float a = md ? bf2f(((const u16*)b_out)[o]) : ((const float*)b_out)[o];
    if(md){
      const u16* wo = (const u16*)w_out + o*U;
      for(int k=0;k<U;k++) a += uout[mm*U + k]*bf2f(wo[k]);
    } else {
      const float* wo = (const float*)w_out + o*U;
      for(int k=0;k<U;k++) a += uout[mm*U + k]*wo[k];
    }
    lg[mm*12 + o] = a;
  }
  __syncthreads();
  if(t < 16){
    float mx = -1e30f;
    for(int o=0;o<10;o++) mx = fmaxf(mx, lg[t*12 + o]);
    float e[10]; float sum = 0.0f;
    for(int o=0;o<10;o++){ e[o] = __expf(lg[t*12 + o] - mx); sum += e[o]; }
    float inv = 1.0f / sum;
    for(int o=0;o<10;o++){
      float pv = e[o]*inv;
      if(md) ((u16*)outraw)[(size_t)(r0 + t)*10 + o] = f2bf(pv);
      else   ((float*)outraw)[(size_t)(r0 + t)*10 + o] = pv;
    }
  }
}

extern "C" void kernel_launch(void* const* d_in, const int* in_sizes, int n_in,
                              void* d_out, int out_size, void* d_ws, size_t ws_size,
                              hipStream_t stream) {
  char* p = (char*)d_ws;
  u16* Fsw = (u16*)p;  p += (size_t)8*256*256*2;   // 1 MB (left half used)
  u16* Wfr = (u16*)p;  p += (size_t)8*128*128*2;   // 256 KB W-row frags

  prepB<<<64, 512, 0, stream>>>(d_in[0], d_in[3], Fsw, Wfr);
  mainG<<<BATCH/16, 512, 0, stream>>>(d_in[0], d_in[1], d_in[2], d_in[4],
                                      (const bf16x8*)Fsw, (const bf16x8*)Wfr,
                                      d_in[5], d_in[6], d_out);
}